// Round 6
// baseline (164.430 us; speedup 1.0000x reference)
//
#include <hip/hip_runtime.h>

// GATv2 x2 + LayerNorm, B=2 N=512 DIN=32 DH=DOUT=64 H=4. fp32 in/out.
// R16 = R15 + bugfix: R15 moved att off LDS to uniform global loads but
// dropped the 0.4 prescale (lrelu(z,.2)=0.6z+0.4|z|; 0.6 is baked into
// sl/sr). Now e = slv + rsr + 0.4*acc via one fmaf per (phase,row).
// R15 structure kept: TI=16 (wave owns 4 i-rows, per-i LDS traffic
// halved), grid 1024 = 4 blocks/CU, uniform operands on scalar pipe,
// LDS = xbuf 32KB + s_p[16][64] 4KB.

#define BB   2
#define NN   512
#define DIN  32
#define DH   64
#define HH   4
#define C1   256
#define C2   256
#define NJC  4     // j-chunks (128 j each)
#define LEPS 1e-5f

typedef unsigned long long u64;

__device__ __forceinline__ float bf_sum(float v) {
#pragma unroll
    for (int o = 32; o > 0; o >>= 1) v += __shfl_xor(v, o, 64);
    return v;
}

__device__ __forceinline__ void gload_lds16(const float* g, float* l) {
    __builtin_amdgcn_global_load_lds(
        (const __attribute__((address_space(1))) void*)g,
        (__attribute__((address_space(3))) void*)l, 16, 0, 0);
}

// --- packed mask: bit j of mask64[i*8 + j/64] = (dot(emb_i,emb_j)!=0 || i==j)
__global__ __launch_bounds__(256) void mask_k(const float* __restrict__ emb,
                                              u64* __restrict__ mask64) {
    __shared__ __align__(16) float s_ei[16][DH];
    __shared__ float ebuf[64][DH + 1];
    int it = blockIdx.x, jq = blockIdx.y;
    int t = threadIdx.x, lane = t & 63, iq = t >> 6;
    int j0 = jq * 64;
    {
        int row = t >> 4, d4 = (t & 15) << 2;
        *(float4*)&s_ei[row][d4] = *(const float4*)(emb + (it * 16 + row) * DH + d4);
    }
#pragma unroll
    for (int k = 0; k < 4; k++) {
        int idx = k * 256 + t, jl = idx >> 4, d4 = (idx & 15) << 2;
        float4 v = *(const float4*)(emb + (j0 + jl) * DH + d4);
        ebuf[jl][d4] = v.x; ebuf[jl][d4 + 1] = v.y;
        ebuf[jl][d4 + 2] = v.z; ebuf[jl][d4 + 3] = v.w;
    }
    __syncthreads();
    float acc[4] = {0.f, 0.f, 0.f, 0.f};
    for (int dc = 0; dc < 16; dc++) {
        int d = dc * 4;
        float e0 = ebuf[lane][d], e1 = ebuf[lane][d + 1];
        float e2 = ebuf[lane][d + 2], e3 = ebuf[lane][d + 3];
#pragma unroll
        for (int r = 0; r < 4; r++) {
            float4 iv = *(const float4*)&s_ei[iq * 4 + r][d];
            acc[r] += iv.x * e0 + iv.y * e1 + iv.z * e2 + iv.w * e3;
        }
    }
    int jg = j0 + lane;
#pragma unroll
    for (int r = 0; r < 4; r++) {
        int ig = it * 16 + iq * 4 + r;
        u64 bal = __ballot(acc[r] != 0.f || ig == jg);
        if (lane == 0) mask64[ig * 8 + jq] = bal;
    }
}

// --- proj1 + fused sl/sr ---
__global__ __launch_bounds__(256) void proj1_k(const float* __restrict__ x,
        const float* __restrict__ wl, const float* __restrict__ bl,
        const float* __restrict__ wr, const float* __restrict__ br,
        const float* __restrict__ att,
        float* __restrict__ xl, float* __restrict__ xr,
        float* __restrict__ sl, float* __restrict__ sr) {
    __shared__ float s_x[4][DIN];
    int t = threadIdx.x, lane = t & 63, row0 = blockIdx.x * 4, cq = blockIdx.y;
    if (t < 128) s_x[t >> 5][t & 31] = x[(row0 + (t >> 5)) * DIN + (t & 31)];
    __syncthreads();
    int cl = t & 127, half = t >> 7;
    int gc = cq * 128 + cl;
    const float* wbase; float bias; float* obase; float* sdst; int oc;
    if (gc < C1) { wbase = wl + gc; bias = bl[gc]; obase = xl; sdst = sl; oc = gc; }
    else         { wbase = wr + gc - C1; bias = br[gc - C1]; obase = xr; sdst = sr; oc = gc - C1; }
    int ra = half * 2, rb = ra + 1;
    float a0 = bias, a1 = bias;
#pragma unroll
    for (int k = 0; k < DIN; k++) {
        float wv = wbase[(size_t)k * C1];
        a0 += s_x[ra][k] * wv;
        a1 += s_x[rb][k] * wv;
    }
    obase[(size_t)(row0 + ra) * C1 + oc] = a0;
    obase[(size_t)(row0 + rb) * C1 + oc] = a1;
    float attv = att[oc];
    float s0 = bf_sum(attv * a0) * 0.6f;
    float s1 = bf_sum(attv * a1) * 0.6f;
    if (lane == 0) {
        int h = oc >> 6;
        int rwa = row0 + ra, rwb = row0 + rb;
        sdst[(h * BB + (rwa >> 9)) * NN + (rwa & 511)] = s0;
        sdst[(h * BB + (rwb >> 9)) * NN + (rwb & 511)] = s1;
    }
}

// --- combine partials + LN(g,be)+ReLU + proj2 + sl/sr ---
__global__ __launch_bounds__(256) void projln_k(const float* __restrict__ pagg,
        const float* __restrict__ plsum, const float* __restrict__ abias,
        const float* __restrict__ g, const float* __restrict__ be,
        const float* __restrict__ wl, const float* __restrict__ bl,
        const float* __restrict__ wr, const float* __restrict__ br,
        const float* __restrict__ att,
        float* __restrict__ xl, float* __restrict__ xr,
        float* __restrict__ sl, float* __restrict__ sr) {
    __shared__ __align__(16) float s_h[4][C1];
    int t = threadIdx.x, lane = t & 63, w = t >> 6;
    int row0 = blockIdx.x * 4, cq = blockIdx.y;
    {
        int rgb = row0 + w;
        int bb = rgb >> 9, ii = rgb & 511;
        int c4 = lane << 2, hh = lane >> 4;
        float vx = 0.f, vy = 0.f, vz = 0.f, vw = 0.f, l = 0.f;
#pragma unroll
        for (int jc = 0; jc < NJC; jc++) {
            float4 a = *(const float4*)(pagg + ((size_t)jc * BB * NN + rgb) * C1 + c4);
            vx += a.x; vy += a.y; vz += a.z; vw += a.w;
            l += plsum[((size_t)jc * HH * BB + hh * BB + bb) * NN + ii];
        }
        float inv = 1.f / l;
        float4 bi = *(const float4*)(abias + c4);
        vx = vx * inv + bi.x; vy = vy * inv + bi.y;
        vz = vz * inv + bi.z; vw = vw * inv + bi.w;
        float mu = bf_sum(vx + vy + vz + vw) * (1.f / 256.f);
        float dx = vx - mu, dy = vy - mu, dz = vz - mu, dw = vw - mu;
        float var = bf_sum(dx * dx + dy * dy + dz * dz + dw * dw) * (1.f / 256.f);
        float rs = rsqrtf(var + LEPS);
        float4 gv = *(const float4*)(g + c4);
        float4 bv = *(const float4*)(be + c4);
        float4 y;
        y.x = fmaxf(dx * rs * gv.x + bv.x, 0.f);
        y.y = fmaxf(dy * rs * gv.y + bv.y, 0.f);
        y.z = fmaxf(dz * rs * gv.z + bv.z, 0.f);
        y.w = fmaxf(dw * rs * gv.w + bv.w, 0.f);
        *(float4*)&s_h[w][c4] = y;
    }
    __syncthreads();
    int cl = t & 127, half = t >> 7;
    int gc = cq * 128 + cl;
    const float* wbase; float bias; float* obase; float* sdst; int oc;
    if (gc < C2) { wbase = wl + gc; bias = bl[gc]; obase = xl; sdst = sl; oc = gc; }
    else         { wbase = wr + gc - C2; bias = br[gc - C2]; obase = xr; sdst = sr; oc = gc - C2; }
    int ra = half * 2, rb = ra + 1;
    float a0 = bias, a1 = bias;
#pragma unroll 8
    for (int k = 0; k < C1; k++) {
        float wv = wbase[(size_t)k * C2];
        a0 += s_h[ra][k] * wv;
        a1 += s_h[rb][k] * wv;
    }
    obase[(size_t)(row0 + ra) * C2 + oc] = a0;
    obase[(size_t)(row0 + rb) * C2 + oc] = a1;
    float attv = att[oc];
    float s0 = bf_sum(attv * a0) * 0.6f;
    float s1 = bf_sum(attv * a1) * 0.6f;
    if (lane == 0) {
        int h = oc >> 6;
        int rwa = row0 + ra, rwb = row0 + rb;
        sdst[(h * BB + (rwa >> 9)) * NN + (rwa & 511)] = s0;
        sdst[(h * BB + (rwb >> 9)) * NN + (rwb & 511)] = s1;
    }
}

// --- GATv2 attention. Block = (16 i-rows, j-chunk 128, h, b). 1024 blocks,
// 4/CU exactly. Wave owns 4 i-rows; thread covers j=ph*64+lane over 2 phases.
// xbuf [128][64] XOR-swizzled (16B slot ^= row&7) via global_load_lds from
// pre-swizzled global src. Uniform operands (xr, att, sr, masks) via
// wave-uniform global addresses -> scalar loads. e = slv + rsr + 0.4*acc
// (0.4 applied ONCE per (phase,row) — R15 forgot it entirely).
__global__ __launch_bounds__(256) void attn_k(const float* __restrict__ xl,
        const float* __restrict__ xr, const float* __restrict__ att,
        const u64* __restrict__ mask64,
        const float* __restrict__ sl, const float* __restrict__ sr,
        float* __restrict__ pagg, float* __restrict__ plsum) {
    __shared__ __align__(16) float xbuf[128 * 64];
    __shared__ __align__(16) float s_p[16][64];

    int bx = blockIdx.x;
    int it = bx >> 2, jc = bx & 3;
    int h = blockIdx.y, b = blockIdx.z;
    int t = threadIdx.x, lane = t & 63;
    int wu = __builtin_amdgcn_readfirstlane(t >> 6);   // wave id in SGPR
    int i0 = it * 16, j0 = jc * 128;

    const float* xlbase = xl + (size_t)b * NN * C1 + h * DH;

    // ---- stage xbuf: wave wu stages rows [wu*32, wu*32+32), 8 x 1KB DMAs ----
    {
        int jr0 = wu * 32;
#pragma unroll
        for (int k = 0; k < 8; k++) {
            int jrow = jr0 + k * 4 + (lane >> 4);
            int dslot = (lane & 15) ^ (jrow & 7);          // pre-swizzled source
            const float* gp = xlbase + (size_t)(j0 + jrow) * C1 + (dslot << 2);
            gload_lds16(gp, &xbuf[(jr0 + k * 4) * 64]);    // wave-uniform dest
        }
    }

    // ---- uniform (scalar-pipe) operands ----
    const float* xrb  = xr + (size_t)(b * NN + i0 + wu * 4) * C1 + h * DH;
    const float* attb = att + h * DH;
    float rsr[4];
#pragma unroll
    for (int r = 0; r < 4; r++) rsr[r] = sr[(h * BB + b) * NN + i0 + wu * 4 + r];

    __syncthreads();

    int swz = lane & 7;
    int c = lane >> 2, e = lane & 3;
    float out[4]  = {0.f, 0.f, 0.f, 0.f};
    float lsum[4] = {0.f, 0.f, 0.f, 0.f};

    for (int ph = 0; ph < 2; ph++) {      // runtime loop: no cross-phase hoisting
        // ---- scores for j = j0 + ph*64 + lane, rows wu*4 .. wu*4+3 ----
        float acc[4] = {0.f, 0.f, 0.f, 0.f};
        const float* xrow = &xbuf[(ph * 64 + lane) * 64];
#pragma unroll 2
        for (int dc = 0; dc < 16; dc++) {
            float4 xv = *(const float4*)(xrow + ((dc ^ swz) << 2));
            float4 av = *(const float4*)(attb + (dc << 2));        // s_load
#pragma unroll
            for (int r = 0; r < 4; r++) {
                float4 rv = *(const float4*)(xrb + r * C1 + (dc << 2));  // s_load
                acc[r] = fmaf(av.x, fabsf(xv.x + rv.x), acc[r]);
                acc[r] = fmaf(av.y, fabsf(xv.y + rv.y), acc[r]);
                acc[r] = fmaf(av.z, fabsf(xv.z + rv.z), acc[r]);
                acc[r] = fmaf(av.w, fabsf(xv.w + rv.w), acc[r]);
            }
        }
        float slv = sl[(h * BB + b) * NN + j0 + ph * 64 + lane];
#pragma unroll
        for (int r = 0; r < 4; r++) {
            u64 m = mask64[(size_t)(i0 + wu * 4 + r) * 8 + jc * 2 + ph];  // s_load
            float e_ = fmaf(0.4f, acc[r], slv + rsr[r]);   // 0.4 * sum(a|z|)
            float p = ((m >> lane) & 1ull) ? __expf(e_) : 0.f;
            lsum[r] += p;
            s_p[wu * 4 + r][lane] = p;
        }
        __threadfence_block();   // s_p rows wave-private: order write->read

        // ---- aggregate: lane = d; out[r] += sum_j p[r][j] * xbuf[j][d] ----
        const float* pb0 = s_p[wu * 4 + 0];
        const float* pb1 = s_p[wu * 4 + 1];
        const float* pb2 = s_p[wu * 4 + 2];
        const float* pb3 = s_p[wu * 4 + 3];
#pragma unroll 4
        for (int j4 = 0; j4 < 16; j4++) {
            int jb = ph * 64 + j4 * 4;
            float x0 = xbuf[(jb + 0) * 64 + (((c ^ ((jb + 0) & 7)) << 2) | e)];
            float x1 = xbuf[(jb + 1) * 64 + (((c ^ ((jb + 1) & 7)) << 2) | e)];
            float x2 = xbuf[(jb + 2) * 64 + (((c ^ ((jb + 2) & 7)) << 2) | e)];
            float x3 = xbuf[(jb + 3) * 64 + (((c ^ ((jb + 3) & 7)) << 2) | e)];
            float4 p0 = *(const float4*)(pb0 + j4 * 4);   // broadcast b128
            float4 p1 = *(const float4*)(pb1 + j4 * 4);
            float4 p2 = *(const float4*)(pb2 + j4 * 4);
            float4 p3 = *(const float4*)(pb3 + j4 * 4);
            out[0] += p0.x * x0 + p0.y * x1 + p0.z * x2 + p0.w * x3;
            out[1] += p1.x * x0 + p1.y * x1 + p1.z * x2 + p1.w * x3;
            out[2] += p2.x * x0 + p2.y * x1 + p2.z * x2 + p2.w * x3;
            out[3] += p3.x * x0 + p3.y * x1 + p3.z * x2 + p3.w * x3;
        }
        __threadfence_block();   // s_p reuse across phases (same wave)
    }

    size_t ob = ((size_t)jc * BB * NN + b * NN + i0 + wu * 4) * C1 + h * DH + lane;
#pragma unroll
    for (int r = 0; r < 4; r++) {
        float l = bf_sum(lsum[r]);
        pagg[ob + (size_t)r * C1] = out[r];
        if (lane == 0)
            plsum[((size_t)jc * HH * BB + h * BB + b) * NN + i0 + wu * 4 + r] = l;
    }
}

// --- combine partials + final LayerNorm, wave-per-row ---
__global__ __launch_bounds__(256) void ln2_k(const float* __restrict__ pagg,
        const float* __restrict__ plsum, const float* __restrict__ abias,
        const float* __restrict__ g, const float* __restrict__ be,
        float* __restrict__ outp) {
    int t = threadIdx.x, lane = t & 63, w = t >> 6;
    int rgb = blockIdx.x * 4 + w;
    int bb = rgb >> 9, ii = rgb & 511;
    int c4 = lane << 2, hh = lane >> 4;
    float vx = 0.f, vy = 0.f, vz = 0.f, vw = 0.f, l = 0.f;
#pragma unroll
    for (int jc = 0; jc < NJC; jc++) {
        float4 a = *(const float4*)(pagg + ((size_t)jc * BB * NN + rgb) * C1 + c4);
        vx += a.x; vy += a.y; vz += a.z; vw += a.w;
        l += plsum[((size_t)jc * HH * BB + hh * BB + bb) * NN + ii];
    }
    float inv = 1.f / l;
    float4 bi = *(const float4*)(abias + c4);
    vx = vx * inv + bi.x; vy = vy * inv + bi.y;
    vz = vz * inv + bi.z; vw = vw * inv + bi.w;
    float mu = bf_sum(vx + vy + vz + vw) * (1.f / 256.f);
    float dx = vx - mu, dy = vy - mu, dz = vz - mu, dw = vw - mu;
    float var = bf_sum(dx * dx + dy * dy + dz * dz + dw * dw) * (1.f / 256.f);
    float rs = rsqrtf(var + LEPS);
    float4 gv = *(const float4*)(g + c4);
    float4 bv = *(const float4*)(be + c4);
    float4 y;
    y.x = dx * rs * gv.x + bv.x;
    y.y = dy * rs * gv.y + bv.y;
    y.z = dz * rs * gv.z + bv.z;
    y.w = dw * rs * gv.w + bv.w;
    *(float4*)(outp + (size_t)rgb * C1 + c4) = y;
}

extern "C" void kernel_launch(void* const* d_in, const int* in_sizes, int n_in,
                              void* d_out, int out_size, void* d_ws, size_t ws_size,
                              hipStream_t stream) {
    const float* x    = (const float*)d_in[0];
    const float* emb  = (const float*)d_in[1];
    const float* w1l  = (const float*)d_in[2];
    const float* b1l  = (const float*)d_in[3];
    const float* w1r  = (const float*)d_in[4];
    const float* b1r  = (const float*)d_in[5];
    const float* att1 = (const float*)d_in[6];
    const float* bia1 = (const float*)d_in[7];
    const float* g1   = (const float*)d_in[8];
    const float* be1  = (const float*)d_in[9];
    const float* w2l  = (const float*)d_in[10];
    const float* b2l  = (const float*)d_in[11];
    const float* w2r  = (const float*)d_in[12];
    const float* b2r  = (const float*)d_in[13];
    const float* att2 = (const float*)d_in[14];
    const float* bia2 = (const float*)d_in[15];
    const float* g2   = (const float*)d_in[16];
    const float* be2  = (const float*)d_in[17];

    char* w = (char*)d_ws;
    float* xl    = (float*)w; w += (size_t)BB * NN * C1 * 4;
    float* xr    = (float*)w; w += (size_t)BB * NN * C1 * 4;
    float* pagg  = (float*)w; w += (size_t)NJC * BB * NN * C1 * 4;
    u64* mask64  = (u64*)w;   w += (size_t)NN * 8 * 8;
    float* plsum = (float*)w; w += (size_t)NJC * HH * BB * NN * 4;
    float* sl    = (float*)w; w += (size_t)HH * BB * NN * 4;
    float* sr    = (float*)w; w += (size_t)HH * BB * NN * 4;

    mask_k<<<dim3(NN / 16, 8), 256, 0, stream>>>(emb, mask64);
    proj1_k<<<dim3(BB * NN / 4, 4), 256, 0, stream>>>(x, w1l, b1l, w1r, b1r, att1, xl, xr, sl, sr);
    attn_k<<<dim3((NN / 16) * NJC, HH, BB), 256, 0, stream>>>(xl, xr, att1, mask64, sl, sr, pagg, plsum);
    projln_k<<<dim3(BB * NN / 4, 4), 256, 0, stream>>>(pagg, plsum, bia1, g1, be1,
                                                       w2l, b2l, w2r, b2r, att2, xl, xr, sl, sr);
    attn_k<<<dim3((NN / 16) * NJC, HH, BB), 256, 0, stream>>>(xl, xr, att2, mask64, sl, sr, pagg, plsum);
    ln2_k<<<BB * NN / 4, 256, 0, stream>>>(pagg, plsum, bia2, g2, be2, (float*)d_out);
}

// Round 7
// 159.413 us; speedup vs baseline: 1.0315x; 1.0315x over previous
//
#include <hip/hip_runtime.h>

// GATv2 x2 + LayerNorm, B=2 N=512 DIN=32 DH=DOUT=64 H=4. fp32 in/out.
// R17: attn_k p-redistribution moved OFF the DS pipe. R13..R16 neutral
// because every variant (s_p b128 broadcast / bpermute / shfl) kept the
// p-transpose on the per-CU LDS pipe (~770cy/wave of 1900). Now p stays
// in the score lanes and the aggregate reads it via v_readlane (VALU,
// SGPR broadcast, compile-time lane indices from full unroll) feeding
// v_fmac with an SGPR multiplier. s_p + fences deleted; LDS = xbuf 32KB.
// DS/wave 1900->~1120cy; attn bound ~13 -> ~8us.

#define BB   2
#define NN   512
#define DIN  32
#define DH   64
#define HH   4
#define C1   256
#define C2   256
#define NJC  4     // j-chunks (128 j each)
#define LEPS 1e-5f

typedef unsigned long long u64;

__device__ __forceinline__ float bf_sum(float v) {
#pragma unroll
    for (int o = 32; o > 0; o >>= 1) v += __shfl_xor(v, o, 64);
    return v;
}

__device__ __forceinline__ void gload_lds16(const float* g, float* l) {
    __builtin_amdgcn_global_load_lds(
        (const __attribute__((address_space(1))) void*)g,
        (__attribute__((address_space(3))) void*)l, 16, 0, 0);
}

__device__ __forceinline__ float rdlane(float v, int l) {
    return __int_as_float(__builtin_amdgcn_readlane(__float_as_int(v), l));
}

// --- packed mask: bit j of mask64[i*8 + j/64] = (dot(emb_i,emb_j)!=0 || i==j)
__global__ __launch_bounds__(256) void mask_k(const float* __restrict__ emb,
                                              u64* __restrict__ mask64) {
    __shared__ __align__(16) float s_ei[16][DH];
    __shared__ float ebuf[64][DH + 1];
    int it = blockIdx.x, jq = blockIdx.y;
    int t = threadIdx.x, lane = t & 63, iq = t >> 6;
    int j0 = jq * 64;
    {
        int row = t >> 4, d4 = (t & 15) << 2;
        *(float4*)&s_ei[row][d4] = *(const float4*)(emb + (it * 16 + row) * DH + d4);
    }
#pragma unroll
    for (int k = 0; k < 4; k++) {
        int idx = k * 256 + t, jl = idx >> 4, d4 = (idx & 15) << 2;
        float4 v = *(const float4*)(emb + (j0 + jl) * DH + d4);
        ebuf[jl][d4] = v.x; ebuf[jl][d4 + 1] = v.y;
        ebuf[jl][d4 + 2] = v.z; ebuf[jl][d4 + 3] = v.w;
    }
    __syncthreads();
    float acc[4] = {0.f, 0.f, 0.f, 0.f};
    for (int dc = 0; dc < 16; dc++) {
        int d = dc * 4;
        float e0 = ebuf[lane][d], e1 = ebuf[lane][d + 1];
        float e2 = ebuf[lane][d + 2], e3 = ebuf[lane][d + 3];
#pragma unroll
        for (int r = 0; r < 4; r++) {
            float4 iv = *(const float4*)&s_ei[iq * 4 + r][d];
            acc[r] += iv.x * e0 + iv.y * e1 + iv.z * e2 + iv.w * e3;
        }
    }
    int jg = j0 + lane;
#pragma unroll
    for (int r = 0; r < 4; r++) {
        int ig = it * 16 + iq * 4 + r;
        u64 bal = __ballot(acc[r] != 0.f || ig == jg);
        if (lane == 0) mask64[ig * 8 + jq] = bal;
    }
}

// --- proj1 + fused sl/sr ---
__global__ __launch_bounds__(256) void proj1_k(const float* __restrict__ x,
        const float* __restrict__ wl, const float* __restrict__ bl,
        const float* __restrict__ wr, const float* __restrict__ br,
        const float* __restrict__ att,
        float* __restrict__ xl, float* __restrict__ xr,
        float* __restrict__ sl, float* __restrict__ sr) {
    __shared__ float s_x[4][DIN];
    int t = threadIdx.x, lane = t & 63, row0 = blockIdx.x * 4, cq = blockIdx.y;
    if (t < 128) s_x[t >> 5][t & 31] = x[(row0 + (t >> 5)) * DIN + (t & 31)];
    __syncthreads();
    int cl = t & 127, half = t >> 7;
    int gc = cq * 128 + cl;
    const float* wbase; float bias; float* obase; float* sdst; int oc;
    if (gc < C1) { wbase = wl + gc; bias = bl[gc]; obase = xl; sdst = sl; oc = gc; }
    else         { wbase = wr + gc - C1; bias = br[gc - C1]; obase = xr; sdst = sr; oc = gc - C1; }
    int ra = half * 2, rb = ra + 1;
    float a0 = bias, a1 = bias;
#pragma unroll
    for (int k = 0; k < DIN; k++) {
        float wv = wbase[(size_t)k * C1];
        a0 += s_x[ra][k] * wv;
        a1 += s_x[rb][k] * wv;
    }
    obase[(size_t)(row0 + ra) * C1 + oc] = a0;
    obase[(size_t)(row0 + rb) * C1 + oc] = a1;
    float attv = att[oc];
    float s0 = bf_sum(attv * a0) * 0.6f;
    float s1 = bf_sum(attv * a1) * 0.6f;
    if (lane == 0) {
        int h = oc >> 6;
        int rwa = row0 + ra, rwb = row0 + rb;
        sdst[(h * BB + (rwa >> 9)) * NN + (rwa & 511)] = s0;
        sdst[(h * BB + (rwb >> 9)) * NN + (rwb & 511)] = s1;
    }
}

// --- combine partials + LN(g,be)+ReLU + proj2 + sl/sr ---
__global__ __launch_bounds__(256) void projln_k(const float* __restrict__ pagg,
        const float* __restrict__ plsum, const float* __restrict__ abias,
        const float* __restrict__ g, const float* __restrict__ be,
        const float* __restrict__ wl, const float* __restrict__ bl,
        const float* __restrict__ wr, const float* __restrict__ br,
        const float* __restrict__ att,
        float* __restrict__ xl, float* __restrict__ xr,
        float* __restrict__ sl, float* __restrict__ sr) {
    __shared__ __align__(16) float s_h[4][C1];
    int t = threadIdx.x, lane = t & 63, w = t >> 6;
    int row0 = blockIdx.x * 4, cq = blockIdx.y;
    {
        int rgb = row0 + w;
        int bb = rgb >> 9, ii = rgb & 511;
        int c4 = lane << 2, hh = lane >> 4;
        float vx = 0.f, vy = 0.f, vz = 0.f, vw = 0.f, l = 0.f;
#pragma unroll
        for (int jc = 0; jc < NJC; jc++) {
            float4 a = *(const float4*)(pagg + ((size_t)jc * BB * NN + rgb) * C1 + c4);
            vx += a.x; vy += a.y; vz += a.z; vw += a.w;
            l += plsum[((size_t)jc * HH * BB + hh * BB + bb) * NN + ii];
        }
        float inv = 1.f / l;
        float4 bi = *(const float4*)(abias + c4);
        vx = vx * inv + bi.x; vy = vy * inv + bi.y;
        vz = vz * inv + bi.z; vw = vw * inv + bi.w;
        float mu = bf_sum(vx + vy + vz + vw) * (1.f / 256.f);
        float dx = vx - mu, dy = vy - mu, dz = vz - mu, dw = vw - mu;
        float var = bf_sum(dx * dx + dy * dy + dz * dz + dw * dw) * (1.f / 256.f);
        float rs = rsqrtf(var + LEPS);
        float4 gv = *(const float4*)(g + c4);
        float4 bv = *(const float4*)(be + c4);
        float4 y;
        y.x = fmaxf(dx * rs * gv.x + bv.x, 0.f);
        y.y = fmaxf(dy * rs * gv.y + bv.y, 0.f);
        y.z = fmaxf(dz * rs * gv.z + bv.z, 0.f);
        y.w = fmaxf(dw * rs * gv.w + bv.w, 0.f);
        *(float4*)&s_h[w][c4] = y;
    }
    __syncthreads();
    int cl = t & 127, half = t >> 7;
    int gc = cq * 128 + cl;
    const float* wbase; float bias; float* obase; float* sdst; int oc;
    if (gc < C2) { wbase = wl + gc; bias = bl[gc]; obase = xl; sdst = sl; oc = gc; }
    else         { wbase = wr + gc - C2; bias = br[gc - C2]; obase = xr; sdst = sr; oc = gc - C2; }
    int ra = half * 2, rb = ra + 1;
    float a0 = bias, a1 = bias;
#pragma unroll 8
    for (int k = 0; k < C1; k++) {
        float wv = wbase[(size_t)k * C2];
        a0 += s_h[ra][k] * wv;
        a1 += s_h[rb][k] * wv;
    }
    obase[(size_t)(row0 + ra) * C2 + oc] = a0;
    obase[(size_t)(row0 + rb) * C2 + oc] = a1;
    float attv = att[oc];
    float s0 = bf_sum(attv * a0) * 0.6f;
    float s1 = bf_sum(attv * a1) * 0.6f;
    if (lane == 0) {
        int h = oc >> 6;
        int rwa = row0 + ra, rwb = row0 + rb;
        sdst[(h * BB + (rwa >> 9)) * NN + (rwa & 511)] = s0;
        sdst[(h * BB + (rwb >> 9)) * NN + (rwb & 511)] = s1;
    }
}

// --- GATv2 attention. Block = (16 i-rows, j-chunk 128, h, b). 1024 blocks,
// 4/CU. Wave owns 4 i-rows; thread covers j=ph*64+lane over 2 phases.
// xbuf [128][64] XOR-swizzled (16B slot ^= row&7) via global_load_lds from
// pre-swizzled global src. Uniform operands on scalar pipe. p never leaves
// registers: aggregate reads it via v_readlane (const lane idx, SGPR
// broadcast into v_fmac) — zero DS-pipe cost for the p-transpose.
__global__ __launch_bounds__(256) void attn_k(const float* __restrict__ xl,
        const float* __restrict__ xr, const float* __restrict__ att,
        const u64* __restrict__ mask64,
        const float* __restrict__ sl, const float* __restrict__ sr,
        float* __restrict__ pagg, float* __restrict__ plsum) {
    __shared__ __align__(16) float xbuf[128 * 64];

    int bx = blockIdx.x;
    int it = bx >> 2, jc = bx & 3;
    int h = blockIdx.y, b = blockIdx.z;
    int t = threadIdx.x, lane = t & 63;
    int wu = __builtin_amdgcn_readfirstlane(t >> 6);   // wave id in SGPR
    int i0 = it * 16, j0 = jc * 128;

    const float* xlbase = xl + (size_t)b * NN * C1 + h * DH;

    // ---- stage xbuf: wave wu stages rows [wu*32, wu*32+32), 8 x 1KB DMAs ----
    {
        int jr0 = wu * 32;
#pragma unroll
        for (int k = 0; k < 8; k++) {
            int jrow = jr0 + k * 4 + (lane >> 4);
            int dslot = (lane & 15) ^ (jrow & 7);          // pre-swizzled source
            const float* gp = xlbase + (size_t)(j0 + jrow) * C1 + (dslot << 2);
            gload_lds16(gp, &xbuf[(jr0 + k * 4) * 64]);    // wave-uniform dest
        }
    }

    // ---- uniform (scalar-pipe) operands ----
    const float* xrb  = xr + (size_t)(b * NN + i0 + wu * 4) * C1 + h * DH;
    const float* attb = att + h * DH;
    float rsr[4];
#pragma unroll
    for (int r = 0; r < 4; r++) rsr[r] = sr[(h * BB + b) * NN + i0 + wu * 4 + r];

    __syncthreads();

    int swz = lane & 7;
    int c = lane >> 2, e = lane & 3;
    float out[4]  = {0.f, 0.f, 0.f, 0.f};
    float lsum[4] = {0.f, 0.f, 0.f, 0.f};

    for (int ph = 0; ph < 2; ph++) {      // runtime loop: no cross-phase hoisting
        // ---- scores for j = j0 + ph*64 + lane, rows wu*4 .. wu*4+3 ----
        float acc[4] = {0.f, 0.f, 0.f, 0.f};
        const float* xrow = &xbuf[(ph * 64 + lane) * 64];
#pragma unroll 2
        for (int dc = 0; dc < 16; dc++) {
            float4 xv = *(const float4*)(xrow + ((dc ^ swz) << 2));
            float4 av = *(const float4*)(attb + (dc << 2));        // s_load
#pragma unroll
            for (int r = 0; r < 4; r++) {
                float4 rv = *(const float4*)(xrb + r * C1 + (dc << 2));  // s_load
                acc[r] = fmaf(av.x, fabsf(xv.x + rv.x), acc[r]);
                acc[r] = fmaf(av.y, fabsf(xv.y + rv.y), acc[r]);
                acc[r] = fmaf(av.z, fabsf(xv.z + rv.z), acc[r]);
                acc[r] = fmaf(av.w, fabsf(xv.w + rv.w), acc[r]);
            }
        }
        float slv = sl[(h * BB + b) * NN + j0 + ph * 64 + lane];
        u64 m0 = mask64[(size_t)(i0 + wu * 4 + 0) * 8 + jc * 2 + ph];  // s_load
        u64 m1 = mask64[(size_t)(i0 + wu * 4 + 1) * 8 + jc * 2 + ph];
        u64 m2 = mask64[(size_t)(i0 + wu * 4 + 2) * 8 + jc * 2 + ph];
        u64 m3 = mask64[(size_t)(i0 + wu * 4 + 3) * 8 + jc * 2 + ph];
        float p0 = ((m0 >> lane) & 1ull) ? __expf(fmaf(0.4f, acc[0], slv + rsr[0])) : 0.f;
        float p1 = ((m1 >> lane) & 1ull) ? __expf(fmaf(0.4f, acc[1], slv + rsr[1])) : 0.f;
        float p2 = ((m2 >> lane) & 1ull) ? __expf(fmaf(0.4f, acc[2], slv + rsr[2])) : 0.f;
        float p3 = ((m3 >> lane) & 1ull) ? __expf(fmaf(0.4f, acc[3], slv + rsr[3])) : 0.f;
        lsum[0] += p0; lsum[1] += p1; lsum[2] += p2; lsum[3] += p3;

        // ---- aggregate: lane = d; out[r] += sum_j p[r][j] * xbuf[j][d].
        // p[r][jl] lives in lane jl; read via v_readlane (const idx, SGPR). ----
#pragma unroll
        for (int j4 = 0; j4 < 16; j4++) {
            int jb = ph * 64 + j4 * 4;
            float x0 = xbuf[(jb + 0) * 64 + (((c ^ ((jb + 0) & 7)) << 2) | e)];
            float x1 = xbuf[(jb + 1) * 64 + (((c ^ ((jb + 1) & 7)) << 2) | e)];
            float x2 = xbuf[(jb + 2) * 64 + (((c ^ ((jb + 2) & 7)) << 2) | e)];
            float x3 = xbuf[(jb + 3) * 64 + (((c ^ ((jb + 3) & 7)) << 2) | e)];
            out[0] += rdlane(p0, j4 * 4 + 0) * x0 + rdlane(p0, j4 * 4 + 1) * x1
                    + rdlane(p0, j4 * 4 + 2) * x2 + rdlane(p0, j4 * 4 + 3) * x3;
            out[1] += rdlane(p1, j4 * 4 + 0) * x0 + rdlane(p1, j4 * 4 + 1) * x1
                    + rdlane(p1, j4 * 4 + 2) * x2 + rdlane(p1, j4 * 4 + 3) * x3;
            out[2] += rdlane(p2, j4 * 4 + 0) * x0 + rdlane(p2, j4 * 4 + 1) * x1
                    + rdlane(p2, j4 * 4 + 2) * x2 + rdlane(p2, j4 * 4 + 3) * x3;
            out[3] += rdlane(p3, j4 * 4 + 0) * x0 + rdlane(p3, j4 * 4 + 1) * x1
                    + rdlane(p3, j4 * 4 + 2) * x2 + rdlane(p3, j4 * 4 + 3) * x3;
        }
    }

    size_t ob = ((size_t)jc * BB * NN + b * NN + i0 + wu * 4) * C1 + h * DH + lane;
#pragma unroll
    for (int r = 0; r < 4; r++) {
        float l = bf_sum(lsum[r]);
        pagg[ob + (size_t)r * C1] = out[r];
        if (lane == 0)
            plsum[((size_t)jc * HH * BB + h * BB + b) * NN + i0 + wu * 4 + r] = l;
    }
}

// --- combine partials + final LayerNorm, wave-per-row ---
__global__ __launch_bounds__(256) void ln2_k(const float* __restrict__ pagg,
        const float* __restrict__ plsum, const float* __restrict__ abias,
        const float* __restrict__ g, const float* __restrict__ be,
        float* __restrict__ outp) {
    int t = threadIdx.x, lane = t & 63, w = t >> 6;
    int rgb = blockIdx.x * 4 + w;
    int bb = rgb >> 9, ii = rgb & 511;
    int c4 = lane << 2, hh = lane >> 4;
    float vx = 0.f, vy = 0.f, vz = 0.f, vw = 0.f, l = 0.f;
#pragma unroll
    for (int jc = 0; jc < NJC; jc++) {
        float4 a = *(const float4*)(pagg + ((size_t)jc * BB * NN + rgb) * C1 + c4);
        vx += a.x; vy += a.y; vz += a.z; vw += a.w;
        l += plsum[((size_t)jc * HH * BB + hh * BB + bb) * NN + ii];
    }
    float inv = 1.f / l;
    float4 bi = *(const float4*)(abias + c4);
    vx = vx * inv + bi.x; vy = vy * inv + bi.y;
    vz = vz * inv + bi.z; vw = vw * inv + bi.w;
    float mu = bf_sum(vx + vy + vz + vw) * (1.f / 256.f);
    float dx = vx - mu, dy = vy - mu, dz = vz - mu, dw = vw - mu;
    float var = bf_sum(dx * dx + dy * dy + dz * dz + dw * dw) * (1.f / 256.f);
    float rs = rsqrtf(var + LEPS);
    float4 gv = *(const float4*)(g + c4);
    float4 bv = *(const float4*)(be + c4);
    float4 y;
    y.x = dx * rs * gv.x + bv.x;
    y.y = dy * rs * gv.y + bv.y;
    y.z = dz * rs * gv.z + bv.z;
    y.w = dw * rs * gv.w + bv.w;
    *(float4*)(outp + (size_t)rgb * C1 + c4) = y;
}

extern "C" void kernel_launch(void* const* d_in, const int* in_sizes, int n_in,
                              void* d_out, int out_size, void* d_ws, size_t ws_size,
                              hipStream_t stream) {
    const float* x    = (const float*)d_in[0];
    const float* emb  = (const float*)d_in[1];
    const float* w1l  = (const float*)d_in[2];
    const float* b1l  = (const float*)d_in[3];
    const float* w1r  = (const float*)d_in[4];
    const float* b1r  = (const float*)d_in[5];
    const float* att1 = (const float*)d_in[6];
    const float* bia1 = (const float*)d_in[7];
    const float* g1   = (const float*)d_in[8];
    const float* be1  = (const float*)d_in[9];
    const float* w2l  = (const float*)d_in[10];
    const float* b2l  = (const float*)d_in[11];
    const float* w2r  = (const float*)d_in[12];
    const float* b2r  = (const float*)d_in[13];
    const float* att2 = (const float*)d_in[14];
    const float* bia2 = (const float*)d_in[15];
    const float* g2   = (const float*)d_in[16];
    const float* be2  = (const float*)d_in[17];

    char* w = (char*)d_ws;
    float* xl    = (float*)w; w += (size_t)BB * NN * C1 * 4;
    float* xr    = (float*)w; w += (size_t)BB * NN * C1 * 4;
    float* pagg  = (float*)w; w += (size_t)NJC * BB * NN * C1 * 4;
    u64* mask64  = (u64*)w;   w += (size_t)NN * 8 * 8;
    float* plsum = (float*)w; w += (size_t)NJC * HH * BB * NN * 4;
    float* sl    = (float*)w; w += (size_t)HH * BB * NN * 4;
    float* sr    = (float*)w; w += (size_t)HH * BB * NN * 4;

    mask_k<<<dim3(NN / 16, 8), 256, 0, stream>>>(emb, mask64);
    proj1_k<<<dim3(BB * NN / 4, 4), 256, 0, stream>>>(x, w1l, b1l, w1r, b1r, att1, xl, xr, sl, sr);
    attn_k<<<dim3((NN / 16) * NJC, HH, BB), 256, 0, stream>>>(xl, xr, att1, mask64, sl, sr, pagg, plsum);
    projln_k<<<dim3(BB * NN / 4, 4), 256, 0, stream>>>(pagg, plsum, bia1, g1, be1,
                                                       w2l, b2l, w2r, b2r, att2, xl, xr, sl, sr);
    attn_k<<<dim3((NN / 16) * NJC, HH, BB), 256, 0, stream>>>(xl, xr, att2, mask64, sl, sr, pagg, plsum);
    ln2_k<<<BB * NN / 4, 256, 0, stream>>>(pagg, plsum, bia2, g2, be2, (float*)d_out);
}